// Round 7
// baseline (23.563 us; speedup 1.0000x reference)
//
#include <hip/hip_runtime.h>

// MMD loss: mean(delta @ delta.T) == ||colsum(source - target)||^2 / N^2.
// O(N*D) streaming reduction (67 MB read).
// R6 lesson: occupancy x pipeline-depth changes (16w/16-deep, 24w/16-deep,
// 32w/8-deep) ALL plateau at 4.2-4.8 TB/s while harness fills stream at
// 6.8 TB/s -> not latency-bound; the column-strided walk (consecutive loads
// stride 4 KB) thrashes DRAM row buffers.
// This version: each wave streams a CONTIGUOUS 8 KB chunk (2 rows) of src
// then the same of tgt; the lane's column rotates (col = (k&3)*64+lane), so
// 4 accumulators per lane cover all 256 float4-columns. 512x512 grid = 4096
// waves = 4096 row-pairs. Epilogue: 8-wave LDS fold -> slice store; finale
// column-partitioned over 64 blocks as before.

#define MMD_N 8192
#define MMD_D 1024
#define CS_BLOCKS 512
#define CS_THREADS 512
#define KD 8                    // 8 x 1 KB loads per array per wave (2 rows)
#define INV_N2 1.4901161193847656e-8f  // 1 / 8192^2

__global__ __launch_bounds__(CS_THREADS) void mmd_colsum(
    const float* __restrict__ src, const float* __restrict__ tgt,
    float* __restrict__ ws, float* __restrict__ out) {
    const int tid  = threadIdx.x;
    const int w    = tid >> 6;    // wave 0..7
    const int lane = tid & 63;
    // wave's chunk: 8 KB = 512 float4 = rows [2*chunk, 2*chunk+1]
    const int chunk = blockIdx.x * 8 + w;
    const float4* s4 = reinterpret_cast<const float4*>(src) + chunk * 512;
    const float4* t4 = reinterpret_cast<const float4*>(tgt) + chunk * 512;

    if (blockIdx.x == 0 && tid == 0) out[0] = 0.f;  // replaces memset node

    // Contiguous per-wave streams: 8 KB of src, then 8 KB of tgt.
    float4 s[KD], t[KD];
#pragma unroll
    for (int k = 0; k < KD; ++k) s[k] = s4[k * 64 + lane];
#pragma unroll
    for (int k = 0; k < KD; ++k) t[k] = t4[k * 64 + lane];

    // Element at load k, lane l has float4-column (k&3)*64 + l.
    float4 acc[4];
#pragma unroll
    for (int m = 0; m < 4; ++m) acc[m] = make_float4(0.f, 0.f, 0.f, 0.f);
#pragma unroll
    for (int k = 0; k < KD; ++k) {
        const int m = k & 3;
        acc[m].x += s[k].x - t[k].x;
        acc[m].y += s[k].y - t[k].y;
        acc[m].z += s[k].z - t[k].z;
        acc[m].w += s[k].w - t[k].w;
    }

    // Cross-wave fold: wave w, lane l owns columns m*64+l (m=0..3).
    __shared__ float4 red[8][256];
#pragma unroll
    for (int m = 0; m < 4; ++m) red[w][m * 64 + lane] = acc[m];
    __syncthreads();
    if (tid < 256) {
        float4 tot = make_float4(0.f, 0.f, 0.f, 0.f);
#pragma unroll
        for (int ww = 0; ww < 8; ++ww) {
            float4 v = red[ww][tid];
            tot.x += v.x; tot.y += v.y; tot.z += v.z; tot.w += v.w;
        }
        // coalesced slice store: block bid owns ws[bid*1024 .. +1023]
        reinterpret_cast<float4*>(ws)[blockIdx.x * 256 + tid] = tot;
    }
}

// 64 blocks x 256 threads. Wave j of block b owns float4-column c = 4b + j;
// lanes split the 512 slices (8 each), shfl-reduce, square, one atomicAdd
// per wave (256 total).
__global__ __launch_bounds__(256) void mmd_finale(
    const float* __restrict__ ws, float* __restrict__ out) {
    const int tid  = threadIdx.x;
    const int j    = tid >> 6;   // wave id 0..3
    const int lane = tid & 63;
    const int c    = blockIdx.x * 4 + j;  // float4 column index 0..255
    const float4* w4 = reinterpret_cast<const float4*>(ws);

    float4 acc = make_float4(0.f, 0.f, 0.f, 0.f);
#pragma unroll
    for (int k = 0; k < CS_BLOCKS / 64; ++k) {  // 8 slices per lane
        float4 v = w4[(lane + 64 * k) * 256 + c];
        acc.x += v.x; acc.y += v.y; acc.z += v.z; acc.w += v.w;
    }
    for (int off = 32; off > 0; off >>= 1) {
        acc.x += __shfl_down(acc.x, off, 64);
        acc.y += __shfl_down(acc.y, off, 64);
        acc.z += __shfl_down(acc.z, off, 64);
        acc.w += __shfl_down(acc.w, off, 64);
    }
    if (lane == 0) {
        float sq = acc.x * acc.x + acc.y * acc.y + acc.z * acc.z + acc.w * acc.w;
        atomicAdd(out, sq * INV_N2);
    }
}

extern "C" void kernel_launch(void* const* d_in, const int* in_sizes, int n_in,
                              void* d_out, int out_size, void* d_ws, size_t ws_size,
                              hipStream_t stream) {
    const float* src = (const float*)d_in[0];
    const float* tgt = (const float*)d_in[1];
    float* out = (float*)d_out;
    float* ws = (float*)d_ws;  // needs CS_BLOCKS * MMD_D floats = 2 MiB

    mmd_colsum<<<CS_BLOCKS, CS_THREADS, 0, stream>>>(src, tgt, ws, out);
    mmd_finale<<<64, 256, 0, stream>>>(ws, out);
}